// Round 2
// baseline (516.602 us; speedup 1.0000x reference)
//
#include <hip/hip_runtime.h>
#include <cstdint>
#include <cstddef>

#define NHEADS 16
#define HD 64
#define SEQ 2048
#define BATCH 4
#define DIMSZ 1024
#define MR (BATCH * SEQ) /* 8192 */

typedef __attribute__((ext_vector_type(8))) short short8;
typedef __attribute__((ext_vector_type(4))) float f32x4;

typedef __attribute__((address_space(1))) const unsigned int as1_u32;
typedef __attribute__((address_space(3))) unsigned int as3_u32;

__device__ __forceinline__ unsigned short f2bf(float x) {
  union { float f; unsigned int u; } v; v.f = x;
  unsigned int r = v.u + 0x7FFFu + ((v.u >> 16) & 1u);
  return (unsigned short)(r >> 16);
}

__device__ __forceinline__ f32x4 mfma16(short8 a, short8 b, f32x4 c) {
  return __builtin_amdgcn_mfma_f32_16x16x32_bf16(a, b, c, 0, 0, 0);
}

__device__ __forceinline__ void gload_lds16(const void* g, void* l) {
  __builtin_amdgcn_global_load_lds((as1_u32*)g, (as3_u32*)l, 16, 0, 0);
}

// XOR swizzle for 128B-row LDS tiles: spreads rows across bank clusters while
// keeping 16B-chunk contiguity (bits 4-6 only). Involution (m231 rule).
__device__ __forceinline__ int swzfn(int r) { return ((r ^ (r >> 3)) & 7) << 4; }

// ---------------- fp32 -> bf16 convert (7 tensors, one launch) ----------------
struct Cvt7 {
  const float* s[7];
  unsigned short* d[7];
  int n4[7];
};

__global__ __launch_bounds__(256) void cvt7_k(Cvt7 a) {
  const int t = blockIdx.y;
  const float4* s = (const float4*)a.s[t];
  ushort4* d = (ushort4*)a.d[t];
  const int n4 = a.n4[t];
  for (int i = blockIdx.x * 256 + threadIdx.x; i < n4; i += gridDim.x * 256) {
    float4 f = s[i];
    ushort4 u;
    u.x = f2bf(f.x); u.y = f2bf(f.y); u.z = f2bf(f.z); u.w = f2bf(f.w);
    d[i] = u;
  }
}

// ---------------- GEMM: C[M,N] = A[M,K] * Bt[N,K]^T + bias ----------------
// m97 structure: 128x128 tile, BK=32, 4 waves (2x2 of 64x64), global_load_lds w16.
struct GemmArgs {
  const unsigned short* A[3];
  const unsigned short* Bt[3];
  const float* bias[3];
  unsigned short* Cb[3];
  float* Cf[3];
};

template <bool BF16OUT>
__global__ __launch_bounds__(256) void gemm_bt_k(GemmArgs g) {
  const int z = blockIdx.z;
  const unsigned short* __restrict__ A = g.A[z];
  const unsigned short* __restrict__ Bt = g.Bt[z];
  const float* __restrict__ bias = g.bias[z];

  __shared__ unsigned short As[128 * 32];
  __shared__ unsigned short Bs[128 * 32];

  const int tid = threadIdx.x;
  const int lane = tid & 63;
  const int wave = tid >> 6;
  const int bm = blockIdx.x * 128;
  const int bn = blockIdx.y * 128;
  const int wm = (wave >> 1) * 64;
  const int wn = (wave & 1) * 64;

  // staging: inst i covers rows i*64 + wave*16 + lane/4, cols (lane%4)*8 .. +8
  const int srow = wave * 16 + (lane >> 2);
  const int scol = (lane & 3) * 8;
  const unsigned short* a_src = A + (size_t)(bm + srow) * DIMSZ + scol;
  const unsigned short* b_src = Bt + (size_t)(bn + srow) * DIMSZ + scol;
  char* a_dst = (char*)As + (size_t)(wave * 16) * 64;  // 64B per row
  char* b_dst = (char*)Bs + (size_t)(wave * 16) * 64;

  const int fr = lane & 15;
  const int fk = (lane >> 4) * 8;

  f32x4 acc[4][4];
#pragma unroll
  for (int m = 0; m < 4; m++)
#pragma unroll
    for (int n = 0; n < 4; n++) acc[m][n] = (f32x4){0.f, 0.f, 0.f, 0.f};

  for (int k0 = 0; k0 < DIMSZ; k0 += 32) {
    __syncthreads();
    gload_lds16(a_src + k0, a_dst);
    gload_lds16(a_src + (size_t)64 * DIMSZ + k0, a_dst + 64 * 64);
    gload_lds16(b_src + k0, b_dst);
    gload_lds16(b_src + (size_t)64 * DIMSZ + k0, b_dst + 64 * 64);
    __syncthreads();

    short8 af[4], bfr[4];
#pragma unroll
    for (int m = 0; m < 4; m++) af[m] = *(const short8*)&As[(wm + m * 16 + fr) * 32 + fk];
#pragma unroll
    for (int n = 0; n < 4; n++) bfr[n] = *(const short8*)&Bs[(wn + n * 16 + fr) * 32 + fk];
#pragma unroll
    for (int m = 0; m < 4; m++)
#pragma unroll
      for (int n = 0; n < 4; n++) acc[m][n] = mfma16(af[m], bfr[n], acc[m][n]);
  }

  // epilogue: C/D layout col=lane&15, row=(lane>>4)*4+j (m89/m91-verified)
  const int r4 = (lane >> 4) * 4;
#pragma unroll
  for (int n = 0; n < 4; n++) {
    const int c = bn + wn + n * 16 + fr;
    const float bv = bias[c];
#pragma unroll
    for (int m = 0; m < 4; m++) {
#pragma unroll
      for (int j = 0; j < 4; j++) {
        const int r = bm + wm + m * 16 + r4 + j;
        const float val = acc[m][n][j] + bv;
        if (BF16OUT)
          g.Cb[z][(size_t)r * DIMSZ + c] = f2bf(val);
        else
          g.Cf[z][(size_t)r * DIMSZ + c] = val;
      }
    }
  }
}

// ---------------- fused attention ----------------
// grid: (SEQ/64, BATCH*NHEADS). 4 waves, each owns 16 q-rows.
// K: global_load_lds w16 with pre-swizzled source (m173); Vt: coalesced short8
// loads + swizzled scalar LDS transpose-writes (2-way banks = free, m136);
// P: per-wave swizzled tile, wave-private (barrier -> s_waitcnt lgkmcnt).
__global__ __launch_bounds__(256) void attn_k(const unsigned short* __restrict__ q,
                                              const unsigned short* __restrict__ k,
                                              const unsigned short* __restrict__ v,
                                              unsigned short* __restrict__ o) {
  const int tid = threadIdx.x;
  const int lane = tid & 63;
  const int wave = tid >> 6;
  const int bh = blockIdx.y;
  const int b = bh >> 4;
  const int h = bh & 15;
  const int q0 = blockIdx.x * 64;

  __shared__ unsigned short Ks[64 * 64];
  __shared__ unsigned short Vt[64 * 64];
  __shared__ unsigned short Ps[4 * 16 * 64];

  const int fr = lane & 15;
  const int fk = (lane >> 4) * 8;
  const int g4 = lane >> 4;

  // Q fragments (registers for the whole kv loop)
  const size_t qrow = (size_t)b * SEQ + q0 + wave * 16 + fr;
  const unsigned short* qp = q + qrow * DIMSZ + h * HD + fk;
  const short8 qa0 = *(const short8*)(qp);
  const short8 qa1 = *(const short8*)(qp + 32);

  float m_run[4], l_run[4];
  f32x4 oacc[4];
#pragma unroll
  for (int j = 0; j < 4; j++) { m_run[j] = -1e30f; l_run[j] = 0.f; }
#pragma unroll
  for (int n = 0; n < 4; n++) oacc[n] = (f32x4){0.f, 0.f, 0.f, 0.f};

  const size_t kvbase = (size_t)b * SEQ * DIMSZ + h * HD;

  // K staging (gload_lds, pre-swizzled source): wave covers rows wave*8+i*32+..
  const int klrow = lane >> 3;         // 0..7
  const int kcb = (lane & 7) * 16;     // linear col-chunk (bytes)
  // V staging: coalesced row reads
  const int vr = tid >> 3;             // 0..31 (+32)
  const int vg = tid & 7;              // col group (8 elems)

  char* KsB = (char*)Ks;
  char* VtB = (char*)Vt;
  char* PsB = (char*)Ps + wave * 2048;
  const int pswz = swzfn(fr);

  for (int kv0 = 0; kv0 < SEQ; kv0 += 64) {
    __syncthreads();  // previous tile's LDS reads complete
    // stage K via global_load_lds (linear LDS dest, swizzled global source)
#pragma unroll
    for (int i = 0; i < 2; i++) {
      const int row = wave * 8 + i * 32 + klrow;
      const unsigned short* src =
          k + kvbase + (size_t)(kv0 + row) * DIMSZ + ((kcb ^ swzfn(row)) >> 1);
      gload_lds16(src, KsB + wave * 1024 + i * 4096);
    }
    // stage V transposed: Vt[d][kv], coalesced global, swizzled LDS writes
#pragma unroll
    for (int i = 0; i < 2; i++) {
      const int r = vr + i * 32;  // kv
      const short8 vd = *(const short8*)(v + kvbase + (size_t)(kv0 + r) * DIMSZ + vg * 8);
#pragma unroll
      for (int j = 0; j < 8; j++) {
        const int c = vg * 8 + j;  // d
        *(unsigned short*)(VtB + ((c * 128 + r * 2) ^ swzfn(c))) = (unsigned short)vd[j];
      }
    }
    __syncthreads();

    // S = Q K^T (per-wave 16x64), fp32 accum
    f32x4 s[4];
#pragma unroll
    for (int n = 0; n < 4; n++) {
      const int row = fr + 16 * n;  // kv in tile
      const int swz = swzfn(row);
      const short8 kb0 = *(const short8*)(KsB + ((row * 128 + fk * 2) ^ swz));
      const short8 kb1 = *(const short8*)(KsB + ((row * 128 + 64 + fk * 2) ^ swz));
      f32x4 t = (f32x4){0.f, 0.f, 0.f, 0.f};
      t = mfma16(qa0, kb0, t);
      t = mfma16(qa1, kb1, t);
      s[n] = t;
    }

    // online softmax (q-rows owned by 16-lane group; reduce over fr lanes)
    float pmax[4];
#pragma unroll
    for (int j = 0; j < 4; j++) {
#pragma unroll
      for (int n = 0; n < 4; n++) s[n][j] *= 0.125f;  // SCALE = 1/sqrt(64)
      float t = fmaxf(fmaxf(s[0][j], s[1][j]), fmaxf(s[2][j], s[3][j]));
      t = fmaxf(t, __shfl_xor(t, 1));
      t = fmaxf(t, __shfl_xor(t, 2));
      t = fmaxf(t, __shfl_xor(t, 4));
      t = fmaxf(t, __shfl_xor(t, 8));
      pmax[j] = t;
    }
    float sf[4];
#pragma unroll
    for (int j = 0; j < 4; j++) {
      const float mn = fmaxf(m_run[j], pmax[j]);
      sf[j] = __expf(m_run[j] - mn);
      m_run[j] = mn;
    }
    float rs[4] = {0.f, 0.f, 0.f, 0.f};
    unsigned short pb[4][4];
#pragma unroll
    for (int n = 0; n < 4; n++)
#pragma unroll
      for (int j = 0; j < 4; j++) {
        const float p = __expf(s[n][j] - m_run[j]);
        rs[j] += p;
        pb[n][j] = f2bf(p);
      }
#pragma unroll
    for (int j = 0; j < 4; j++) {
      float t = rs[j];
      t += __shfl_xor(t, 1);
      t += __shfl_xor(t, 2);
      t += __shfl_xor(t, 4);
      t += __shfl_xor(t, 8);
      l_run[j] = l_run[j] * sf[j] + t;
    }
#pragma unroll
    for (int n = 0; n < 4; n++)
#pragma unroll
      for (int j = 0; j < 4; j++) oacc[n][j] *= sf[j];

    // write P (bf16) to per-wave LDS tile; S layout: row=g4*4+j, col=fr+16n
#pragma unroll
    for (int n = 0; n < 4; n++)
#pragma unroll
      for (int j = 0; j < 4; j++) {
        const int row = g4 * 4 + j;
        const int col = fr + 16 * n;
        *(unsigned short*)(PsB + ((row * 128 + col * 2) ^ swzfn(row))) = pb[n][j];
      }
    // P is wave-private: in-order per-wave DS completion suffices (no barrier)
    asm volatile("s_waitcnt lgkmcnt(0)" ::: "memory");

    // O += P V
    const short8 pa0 = *(const short8*)(PsB + ((fr * 128 + fk * 2) ^ pswz));
    const short8 pa1 = *(const short8*)(PsB + ((fr * 128 + 64 + fk * 2) ^ pswz));
#pragma unroll
    for (int n = 0; n < 4; n++) {
      const int row = fr + 16 * n;  // d
      const int swz = swzfn(row);
      const short8 vb0 = *(const short8*)(VtB + ((row * 128 + fk * 2) ^ swz));
      const short8 vb1 = *(const short8*)(VtB + ((row * 128 + 64 + fk * 2) ^ swz));
      oacc[n] = mfma16(pa0, vb0, oacc[n]);
      oacc[n] = mfma16(pa1, vb1, oacc[n]);
    }
  }

  // epilogue: o in [(bh), n, d] flat order == reference's raw reshape
#pragma unroll
  for (int n = 0; n < 4; n++)
#pragma unroll
    for (int j = 0; j < 4; j++) {
      const int row = q0 + wave * 16 + g4 * 4 + j;
      const int col = fr + 16 * n;
      const float val = oacc[n][j] / l_run[j];
      o[((size_t)bh * SEQ + row) * HD + col] = f2bf(val);
    }
}

// ---------------- launcher ----------------
extern "C" void kernel_launch(void* const* d_in, const int* in_sizes, int n_in,
                              void* d_out, int out_size, void* d_ws, size_t ws_size,
                              hipStream_t stream) {
  (void)in_sizes; (void)n_in; (void)out_size; (void)ws_size;
  const float* query = (const float*)d_in[0];
  const float* key_i = (const float*)d_in[1];
  const float* value = (const float*)d_in[2];
  const float* Wq = (const float*)d_in[3];
  const float* bq = (const float*)d_in[4];
  const float* Wk = (const float*)d_in[5];
  const float* bk = (const float*)d_in[6];
  const float* Wv = (const float*)d_in[7];
  const float* bv = (const float*)d_in[8];
  const float* Wo = (const float*)d_in[9];
  const float* bo = (const float*)d_in[10];
  float* out = (float*)d_out;

  char* ws = (char*)d_ws;
  size_t off = 0;
  auto alloc = [&](size_t bytes) -> char* {
    char* p = ws + off;
    off += (bytes + 255) & ~(size_t)255;
    return p;
  };
  const size_t big = (size_t)MR * DIMSZ * 2;      // 16.78 MB
  const size_t wsz = (size_t)DIMSZ * DIMSZ * 2;   // 2.1 MB
  unsigned short* xq = (unsigned short*)alloc(big);
  unsigned short* xk = (unsigned short*)alloc(big);
  unsigned short* xv = (unsigned short*)alloc(big);
  unsigned short* wqb = (unsigned short*)alloc(wsz);
  unsigned short* wkb = (unsigned short*)alloc(wsz);
  unsigned short* wvb = (unsigned short*)alloc(wsz);
  unsigned short* wob = (unsigned short*)alloc(wsz);
  unsigned short* qb = (unsigned short*)alloc(big);
  unsigned short* kb = (unsigned short*)alloc(big);
  unsigned short* vb = (unsigned short*)alloc(big);
  unsigned short* ob = xq;  // xq dead after QKV GEMM; alias to shrink ws need

  // 1) convert inputs + weights to bf16
  Cvt7 ca;
  ca.s[0] = query; ca.d[0] = xq; ca.n4[0] = MR * DIMSZ / 4;
  ca.s[1] = key_i; ca.d[1] = xk; ca.n4[1] = MR * DIMSZ / 4;
  ca.s[2] = value; ca.d[2] = xv; ca.n4[2] = MR * DIMSZ / 4;
  ca.s[3] = Wq;    ca.d[3] = wqb; ca.n4[3] = DIMSZ * DIMSZ / 4;
  ca.s[4] = Wk;    ca.d[4] = wkb; ca.n4[4] = DIMSZ * DIMSZ / 4;
  ca.s[5] = Wv;    ca.d[5] = wvb; ca.n4[5] = DIMSZ * DIMSZ / 4;
  ca.s[6] = Wo;    ca.d[6] = wob; ca.n4[6] = DIMSZ * DIMSZ / 4;
  cvt7_k<<<dim3(1024, 7), 256, 0, stream>>>(ca);

  // 2) QKV projections (z-fused)
  GemmArgs gp;
  gp.A[0] = xq; gp.A[1] = xk; gp.A[2] = xv;
  gp.Bt[0] = wqb; gp.Bt[1] = wkb; gp.Bt[2] = wvb;
  gp.bias[0] = bq; gp.bias[1] = bk; gp.bias[2] = bv;
  gp.Cb[0] = qb; gp.Cb[1] = kb; gp.Cb[2] = vb;
  gp.Cf[0] = nullptr; gp.Cf[1] = nullptr; gp.Cf[2] = nullptr;
  gemm_bt_k<true><<<dim3(MR / 128, DIMSZ / 128, 3), 256, 0, stream>>>(gp);

  // 3) fused attention (writes ob, which aliases xq — xq fully consumed above)
  attn_k<<<dim3(SEQ / 64, BATCH * NHEADS), 256, 0, stream>>>(qb, kb, vb, ob);

  // 4) output projection (fp32 out + bias)
  GemmArgs go;
  go.A[0] = ob; go.A[1] = ob; go.A[2] = ob;
  go.Bt[0] = wob; go.Bt[1] = wob; go.Bt[2] = wob;
  go.bias[0] = bo; go.bias[1] = bo; go.bias[2] = bo;
  go.Cb[0] = nullptr; go.Cb[1] = nullptr; go.Cb[2] = nullptr;
  go.Cf[0] = out; go.Cf[1] = out; go.Cf[2] = out;
  gemm_bt_k<false><<<dim3(MR / 128, DIMSZ / 128, 1), 256, 0, stream>>>(go);
}

// Round 5
// 424.082 us; speedup vs baseline: 1.2182x; 1.2182x over previous
//
#include <hip/hip_runtime.h>
#include <cstdint>
#include <cstddef>

#define NHEADS 16
#define HD 64
#define SEQ 2048
#define BATCH 4
#define DIMSZ 1024
#define MR (BATCH * SEQ) /* 8192 */

typedef __attribute__((ext_vector_type(8))) short short8;
typedef __attribute__((ext_vector_type(4))) float f32x4;

typedef __attribute__((address_space(1))) const unsigned int as1_u32;
typedef __attribute__((address_space(3))) unsigned int as3_u32;

__device__ __forceinline__ unsigned short f2bf(float x) {
  union { float f; unsigned int u; } v; v.f = x;
  unsigned int r = v.u + 0x7FFFu + ((v.u >> 16) & 1u);
  return (unsigned short)(r >> 16);
}

__device__ __forceinline__ f32x4 mfma16(short8 a, short8 b, f32x4 c) {
  return __builtin_amdgcn_mfma_f32_16x16x32_bf16(a, b, c, 0, 0, 0);
}

__device__ __forceinline__ void gload_lds16(const void* g, void* l) {
  __builtin_amdgcn_global_load_lds((as1_u32*)g, (as3_u32*)l, 16, 0, 0);
}

// XOR swizzle for 128B-row LDS tiles (bits 4-6; involution).
__device__ __forceinline__ int swzfn(int r) { return ((r ^ (r >> 3)) & 7) << 4; }

// ---------------- fp32 -> bf16 convert ----------------
struct Cvt7 {
  const float* s[7];
  unsigned short* d[7];
  int n4[7];
};

__global__ __launch_bounds__(256) void cvt7_k(Cvt7 a) {
  const int t = blockIdx.y;
  const float4* s = (const float4*)a.s[t];
  ushort4* d = (ushort4*)a.d[t];
  const int n4 = a.n4[t];
  for (int i = blockIdx.x * 256 + threadIdx.x; i < n4; i += gridDim.x * 256) {
    float4 f = s[i];
    ushort4 u;
    u.x = f2bf(f.x); u.y = f2bf(f.y); u.z = f2bf(f.z); u.w = f2bf(f.w);
    d[i] = u;
  }
}

// ---------------- GEMM: C[M,N] = A[M,K] * Bt[N,K]^T + bias ----------------
struct GemmArgs {
  const unsigned short* A[3];
  const unsigned short* Bt[3];
  const float* bias[3];
  unsigned short* Cb[3];
  float* Cf[3];
  float scale[3];
  int vt[3];  // 1 => write bf16 output transposed per-head: vt[bh][d][kv]
};

template <bool BF16OUT>
__global__ __launch_bounds__(256) void gemm_bt_k(GemmArgs g) {
  const int z = blockIdx.z;
  const unsigned short* __restrict__ A = g.A[z];
  const unsigned short* __restrict__ Bt = g.Bt[z];
  const float* __restrict__ bias = g.bias[z];

  __shared__ unsigned short As[128 * 32];
  __shared__ unsigned short Bs[128 * 32];

  const int tid = threadIdx.x;
  const int lane = tid & 63;
  const int wave = tid >> 6;
  const int bm = blockIdx.x * 128;
  const int bn = blockIdx.y * 128;
  const int wm = (wave >> 1) * 64;
  const int wn = (wave & 1) * 64;

  const int srow = wave * 16 + (lane >> 2);
  const int scol = (lane & 3) * 8;
  const unsigned short* a_src = A + (size_t)(bm + srow) * DIMSZ + scol;
  const unsigned short* b_src = Bt + (size_t)(bn + srow) * DIMSZ + scol;
  char* a_dst = (char*)As + (size_t)(wave * 16) * 64;
  char* b_dst = (char*)Bs + (size_t)(wave * 16) * 64;

  const int fr = lane & 15;
  const int fk = (lane >> 4) * 8;

  f32x4 acc[4][4];
#pragma unroll
  for (int m = 0; m < 4; m++)
#pragma unroll
    for (int n = 0; n < 4; n++) acc[m][n] = (f32x4){0.f, 0.f, 0.f, 0.f};

  for (int k0 = 0; k0 < DIMSZ; k0 += 32) {
    __syncthreads();
    gload_lds16(a_src + k0, a_dst);
    gload_lds16(a_src + (size_t)64 * DIMSZ + k0, a_dst + 64 * 64);
    gload_lds16(b_src + k0, b_dst);
    gload_lds16(b_src + (size_t)64 * DIMSZ + k0, b_dst + 64 * 64);
    __syncthreads();

    short8 af[4], bfr[4];
#pragma unroll
    for (int m = 0; m < 4; m++) af[m] = *(const short8*)&As[(wm + m * 16 + fr) * 32 + fk];
#pragma unroll
    for (int n = 0; n < 4; n++) bfr[n] = *(const short8*)&Bs[(wn + n * 16 + fr) * 32 + fk];
#pragma unroll
    for (int m = 0; m < 4; m++)
#pragma unroll
      for (int n = 0; n < 4; n++) acc[m][n] = mfma16(af[m], bfr[n], acc[m][n]);
  }

  // epilogue: C/D layout col=lane&15, row=(lane>>4)*4+j (m89/m91-verified)
  const int r4 = (lane >> 4) * 4;
  const float sc = g.scale[z];
  if (g.vt[z]) {
    // write V^T per-head: vt[(b*16+h)*64 + d][kv], 4 consecutive rows packed
    unsigned short* vtp = g.Cb[z];
#pragma unroll
    for (int n = 0; n < 4; n++) {
      const int c = bn + wn + n * 16 + fr;
      const float bv = bias[c];
#pragma unroll
      for (int m = 0; m < 4; m++) {
        const int rr = bm + wm + m * 16 + r4;
        ushort4 u;
        u.x = f2bf((acc[m][n][0] + bv) * sc);
        u.y = f2bf((acc[m][n][1] + bv) * sc);
        u.z = f2bf((acc[m][n][2] + bv) * sc);
        u.w = f2bf((acc[m][n][3] + bv) * sc);
        const size_t idx =
            ((size_t)((rr >> 11) * NHEADS + (c >> 6)) * HD + (c & 63)) * SEQ + (rr & (SEQ - 1));
        *(ushort4*)&vtp[idx] = u;
      }
    }
  } else {
#pragma unroll
    for (int n = 0; n < 4; n++) {
      const int c = bn + wn + n * 16 + fr;
      const float bv = bias[c];
#pragma unroll
      for (int m = 0; m < 4; m++) {
#pragma unroll
        for (int j = 0; j < 4; j++) {
          const int r = bm + wm + m * 16 + r4 + j;
          const float val = (acc[m][n][j] + bv) * sc;
          if (BF16OUT)
            g.Cb[z][(size_t)r * DIMSZ + c] = f2bf(val);
          else
            g.Cf[z][(size_t)r * DIMSZ + c] = val;
        }
      }
    }
  }
}

// ---------------- fused attention (swapped-QK, in-register P, dbuf) ----------------
// grid (SEQ/64, 64 bh); 4 waves × 16 q-rows. K and V^T staged via global_load_lds
// (pre-swizzled source), double-buffered; softmax lane-local (swapped QK);
// P redistributed to PV A-fragments with 8 shfl; 1 barrier per tile.
__global__ __launch_bounds__(256) void attn_k(const unsigned short* __restrict__ q,
                                              const unsigned short* __restrict__ k,
                                              const unsigned short* __restrict__ vt,
                                              unsigned short* __restrict__ o) {
  const int tid = threadIdx.x;
  const int lane = tid & 63;
  const int wave = tid >> 6;
  const int bh = blockIdx.y;
  const int b = bh >> 4;
  const int h = bh & 15;
  const int q0 = blockIdx.x * 64;

  __shared__ unsigned short Ks[2][64 * 64];
  __shared__ unsigned short Vs[2][64 * 64];

  const int fr = lane & 15;
  const int g4 = lane >> 4;
  const int fkb = g4 * 16;  // fragment k-chunk byte offset

  // Q fragments (Q pre-scaled by 0.125 in the projection GEMM)
  const size_t qrow = (size_t)b * SEQ + q0 + wave * 16 + fr;
  const unsigned short* qp = q + qrow * DIMSZ + h * HD + g4 * 8;
  const short8 qa0 = *(const short8*)(qp);
  const short8 qa1 = *(const short8*)(qp + 32);

  float m_run = -1e30f, l_run = 0.f;
  f32x4 oacc[4];
#pragma unroll
  for (int n = 0; n < 4; n++) oacc[n] = (f32x4){0.f, 0.f, 0.f, 0.f};

  const size_t kvbase = (size_t)b * SEQ * DIMSZ + h * HD;
  const size_t vtbase = (size_t)bh * HD * SEQ;  // vt[bh][d][kv]
  const int klrow = lane >> 3;       // 0..7
  const int kcb = (lane & 7) * 16;   // chunk byte offset within 128B row

  auto stage = [&](int t, int buf) {
    const int kv0 = t * 64;
#pragma unroll
    for (int i = 0; i < 2; i++) {
      const int row = wave * 8 + i * 32 + klrow;
      const int scol = (kcb ^ swzfn(row)) >> 1;  // pre-swizzled source (elements)
      gload_lds16(k + kvbase + (size_t)(kv0 + row) * DIMSZ + scol,
                  (char*)Ks[buf] + (wave * 8 + i * 32) * 128);
      gload_lds16(vt + vtbase + (size_t)row * SEQ + kv0 + scol,
                  (char*)Vs[buf] + (wave * 8 + i * 32) * 128);
    }
  };

  stage(0, 0);
  __syncthreads();
  int cur = 0;

  for (int t = 0; t < SEQ / 64; ++t) {
    if (t + 1 < SEQ / 64) stage(t + 1, cur ^ 1);

    const char* Kc = (const char*)Ks[cur];
    const char* Vc = (const char*)Vs[cur];

    // S^T = K·Q^T : lane holds S[kv = 16n + 4*g4 + jj][q = fr]
    f32x4 s[4];
#pragma unroll
    for (int n = 0; n < 4; n++) {
      const int row = fr + 16 * n;
      const int swz = swzfn(row);
      const short8 kb0 = *(const short8*)(Kc + ((row * 128 + fkb) ^ swz));
      const short8 kb1 = *(const short8*)(Kc + ((row * 128 + 64 + fkb) ^ swz));
      f32x4 tacc = (f32x4){0.f, 0.f, 0.f, 0.f};
      tacc = mfma16(kb0, qa0, tacc);
      tacc = mfma16(kb1, qa1, tacc);
      s[n] = tacc;
    }

    // lane-local softmax for q-row fr (combine the 4 g4 copies via 2 shfl)
    float pm = -1e30f;
#pragma unroll
    for (int n = 0; n < 4; n++)
#pragma unroll
      for (int jj = 0; jj < 4; jj++) pm = fmaxf(pm, s[n][jj]);
    pm = fmaxf(pm, __shfl_xor(pm, 16));
    pm = fmaxf(pm, __shfl_xor(pm, 32));
    const float mn = fmaxf(m_run, pm);
    const float sf = __expf(m_run - mn);
    m_run = mn;

    float pe[4][4];
    float rs = 0.f;
#pragma unroll
    for (int n = 0; n < 4; n++)
#pragma unroll
      for (int jj = 0; jj < 4; jj++) {
        const float p = __expf(s[n][jj] - mn);
        pe[n][jj] = p;
        rs += p;
      }
    rs += __shfl_xor(rs, 16);
    rs += __shfl_xor(rs, 32);
    l_run = l_run * sf + rs;

    // pack P to bf16 pairs: P32[n][h] = (kv=16n+4g4+2h, +1)
    unsigned P32[4][2];
#pragma unroll
    for (int n = 0; n < 4; n++) {
      P32[n][0] = (unsigned)f2bf(pe[n][0]) | ((unsigned)f2bf(pe[n][1]) << 16);
      P32[n][1] = (unsigned)f2bf(pe[n][2]) | ((unsigned)f2bf(pe[n][3]) << 16);
    }

    // redistribute to PV A-fragment layout: lane needs P[q=fr][kv = 8*g4+jj (+32)]
    const int myn = g4 & 1;
    const int srcA = fr + 16 * ((g4 & 1) * 2 + (g4 >> 1));
    const int srcB = fr + 16 * ((g4 & 1) * 2 + ((g4 >> 1) ^ 1));
    const unsigned xA0 = myn ? P32[1][0] : P32[0][0];
    const unsigned xA1 = myn ? P32[1][1] : P32[0][1];
    const unsigned xB0 = myn ? P32[0][0] : P32[1][0];
    const unsigned xB1 = myn ? P32[0][1] : P32[1][1];
    const unsigned xC0 = myn ? P32[3][0] : P32[2][0];
    const unsigned xC1 = myn ? P32[3][1] : P32[2][1];
    const unsigned xD0 = myn ? P32[2][0] : P32[3][0];
    const unsigned xD1 = myn ? P32[2][1] : P32[3][1];
    const unsigned A0 = (unsigned)__shfl((int)xA0, srcA);
    const unsigned A1 = (unsigned)__shfl((int)xA1, srcA);
    const unsigned B0 = (unsigned)__shfl((int)xB0, srcB);
    const unsigned B1 = (unsigned)__shfl((int)xB1, srcB);
    const unsigned C0 = (unsigned)__shfl((int)xC0, srcA);
    const unsigned C1 = (unsigned)__shfl((int)xC1, srcA);
    const unsigned D0 = (unsigned)__shfl((int)xD0, srcB);
    const unsigned D1 = (unsigned)__shfl((int)xD1, srcB);

    const bool lohalf = (g4 < 2);
    union { unsigned u[4]; short8 v; } pa0, pa1;
    pa0.u[0] = lohalf ? A0 : B0;
    pa0.u[1] = lohalf ? A1 : B1;
    pa0.u[2] = lohalf ? B0 : A0;
    pa0.u[3] = lohalf ? B1 : A1;
    pa1.u[0] = lohalf ? C0 : D0;
    pa1.u[1] = lohalf ? C1 : D1;
    pa1.u[2] = lohalf ? D0 : C0;
    pa1.u[3] = lohalf ? D1 : C1;

    // rescale O (rows 4*g4+jj): gather sf of those rows
    float sfr[4];
#pragma unroll
    for (int jj = 0; jj < 4; jj++) sfr[jj] = __shfl(sf, 20 * g4 + jj);
#pragma unroll
    for (int n = 0; n < 4; n++)
#pragma unroll
      for (int jj = 0; jj < 4; jj++) oacc[n][jj] *= sfr[jj];

    // O += P V  (B-operand = V^T tile rows)
#pragma unroll
    for (int n = 0; n < 4; n++) {
      const int row = fr + 16 * n;  // d
      const int swz = swzfn(row);
      const short8 vb0 = *(const short8*)(Vc + ((row * 128 + fkb) ^ swz));
      const short8 vb1 = *(const short8*)(Vc + ((row * 128 + 64 + fkb) ^ swz));
      oacc[n] = mfma16(pa0.v, vb0, oacc[n]);
      oacc[n] = mfma16(pa1.v, vb1, oacc[n]);
    }

    __syncthreads();  // next-tile staging complete; cur buffer free for reuse
    cur ^= 1;
  }

  // epilogue: rows q = q0 + wave*16 + 4*g4 + jj, col d = fr + 16*n
  float lr[4];
#pragma unroll
  for (int jj = 0; jj < 4; jj++) lr[jj] = __shfl(l_run, 20 * g4 + jj);
#pragma unroll
  for (int n = 0; n < 4; n++)
#pragma unroll
    for (int jj = 0; jj < 4; jj++) {
      const int row = q0 + wave * 16 + 4 * g4 + jj;
      const float val = oacc[n][jj] / lr[jj];
      o[((size_t)bh * SEQ + row) * HD + fr + 16 * n] = f2bf(val);
    }
}

// ---------------- launcher ----------------
extern "C" void kernel_launch(void* const* d_in, const int* in_sizes, int n_in,
                              void* d_out, int out_size, void* d_ws, size_t ws_size,
                              hipStream_t stream) {
  (void)in_sizes; (void)n_in; (void)out_size; (void)ws_size;
  const float* query = (const float*)d_in[0];
  const float* key_i = (const float*)d_in[1];
  const float* value = (const float*)d_in[2];
  const float* Wq = (const float*)d_in[3];
  const float* bq = (const float*)d_in[4];
  const float* Wk = (const float*)d_in[5];
  const float* bk = (const float*)d_in[6];
  const float* Wv = (const float*)d_in[7];
  const float* bv = (const float*)d_in[8];
  const float* Wo = (const float*)d_in[9];
  const float* bo = (const float*)d_in[10];
  float* out = (float*)d_out;

  char* ws = (char*)d_ws;
  size_t off = 0;
  auto alloc = [&](size_t bytes) -> char* {
    char* p = ws + off;
    off += (bytes + 255) & ~(size_t)255;
    return p;
  };
  const size_t big = (size_t)MR * DIMSZ * 2;      // 16.78 MB
  const size_t wsz = (size_t)DIMSZ * DIMSZ * 2;   // 2.1 MB
  unsigned short* xq = (unsigned short*)alloc(big);
  unsigned short* xk = (unsigned short*)alloc(big);
  unsigned short* xv = (unsigned short*)alloc(big);
  unsigned short* wqb = (unsigned short*)alloc(wsz);
  unsigned short* wkb = (unsigned short*)alloc(wsz);
  unsigned short* wvb = (unsigned short*)alloc(wsz);
  unsigned short* wob = (unsigned short*)alloc(wsz);
  unsigned short* qb = (unsigned short*)alloc(big);
  unsigned short* kb = (unsigned short*)alloc(big);
  unsigned short* vtb = (unsigned short*)alloc(big);  // V^T per-head [bh][d][kv]
  unsigned short* ob = xq;  // xq dead after QKV GEMM

  // 1) convert inputs + weights to bf16
  Cvt7 ca;
  ca.s[0] = query; ca.d[0] = xq; ca.n4[0] = MR * DIMSZ / 4;
  ca.s[1] = key_i; ca.d[1] = xk; ca.n4[1] = MR * DIMSZ / 4;
  ca.s[2] = value; ca.d[2] = xv; ca.n4[2] = MR * DIMSZ / 4;
  ca.s[3] = Wq;    ca.d[3] = wqb; ca.n4[3] = DIMSZ * DIMSZ / 4;
  ca.s[4] = Wk;    ca.d[4] = wkb; ca.n4[4] = DIMSZ * DIMSZ / 4;
  ca.s[5] = Wv;    ca.d[5] = wvb; ca.n4[5] = DIMSZ * DIMSZ / 4;
  ca.s[6] = Wo;    ca.d[6] = wob; ca.n4[6] = DIMSZ * DIMSZ / 4;
  cvt7_k<<<dim3(1024, 7), 256, 0, stream>>>(ca);

  // 2) QKV projections (z-fused); Q pre-scaled by 0.125; V written transposed
  GemmArgs gp;
  gp.A[0] = xq; gp.A[1] = xk; gp.A[2] = xv;
  gp.Bt[0] = wqb; gp.Bt[1] = wkb; gp.Bt[2] = wvb;
  gp.bias[0] = bq; gp.bias[1] = bk; gp.bias[2] = bv;
  gp.Cb[0] = qb; gp.Cb[1] = kb; gp.Cb[2] = vtb;
  gp.Cf[0] = nullptr; gp.Cf[1] = nullptr; gp.Cf[2] = nullptr;
  gp.scale[0] = 0.125f; gp.scale[1] = 1.f; gp.scale[2] = 1.f;
  gp.vt[0] = 0; gp.vt[1] = 0; gp.vt[2] = 1;
  gemm_bt_k<true><<<dim3(MR / 128, DIMSZ / 128, 3), 256, 0, stream>>>(gp);

  // 3) fused attention
  attn_k<<<dim3(SEQ / 64, BATCH * NHEADS), 256, 0, stream>>>(qb, kb, vtb, ob);

  // 4) output projection (fp32 out + bias)
  GemmArgs go;
  go.A[0] = ob; go.A[1] = ob; go.A[2] = ob;
  go.Bt[0] = wob; go.Bt[1] = wob; go.Bt[2] = wob;
  go.bias[0] = bo; go.bias[1] = bo; go.bias[2] = bo;
  go.Cb[0] = nullptr; go.Cb[1] = nullptr; go.Cb[2] = nullptr;
  go.Cf[0] = out; go.Cf[1] = out; go.Cf[2] = out;
  go.scale[0] = 1.f; go.scale[1] = 1.f; go.scale[2] = 1.f;
  go.vt[0] = 0; go.vt[1] = 0; go.vt[2] = 0;
  gemm_bt_k<false><<<dim3(MR / 128, DIMSZ / 128, 1), 256, 0, stream>>>(go);
}

// Round 8
// 391.905 us; speedup vs baseline: 1.3182x; 1.0821x over previous
//
#include <hip/hip_runtime.h>
#include <cstdint>
#include <cstddef>

#define NHEADS 16
#define HD 64
#define SEQ 2048
#define BATCH 4
#define DIMSZ 1024
#define MR (BATCH * SEQ) /* 8192 */

typedef __attribute__((ext_vector_type(8))) short short8;
typedef __attribute__((ext_vector_type(4))) short short4v;
typedef __attribute__((ext_vector_type(4))) float f32x4;

typedef __attribute__((address_space(1))) const unsigned int as1_u32;
typedef __attribute__((address_space(3))) unsigned int as3_u32;

__device__ __forceinline__ unsigned short f2bf(float x) {
  union { float f; unsigned int u; } v; v.f = x;
  unsigned int r = v.u + 0x7FFFu + ((v.u >> 16) & 1u);
  return (unsigned short)(r >> 16);
}

__device__ __forceinline__ f32x4 mfma16(short8 a, short8 b, f32x4 c) {
  return __builtin_amdgcn_mfma_f32_16x16x32_bf16(a, b, c, 0, 0, 0);
}

__device__ __forceinline__ void gload_lds16(const void* g, void* l) {
  __builtin_amdgcn_global_load_lds((as1_u32*)g, (as3_u32*)l, 16, 0, 0);
}

// XOR swizzle for 128B-row LDS tiles (bits 4-6; involution).
__device__ __forceinline__ int swzfn(int r) { return ((r ^ (r >> 3)) & 7) << 4; }

// ---------------- fp32 -> bf16 convert ----------------
struct Cvt7 {
  const float* s[7];
  unsigned short* d[7];
  int n4[7];
};

__global__ __launch_bounds__(256) void cvt7_k(Cvt7 a) {
  const int t = blockIdx.y;
  const float4* s = (const float4*)a.s[t];
  ushort4* d = (ushort4*)a.d[t];
  const int n4 = a.n4[t];
  for (int i = blockIdx.x * 256 + threadIdx.x; i < n4; i += gridDim.x * 256) {
    float4 f = s[i];
    ushort4 u;
    u.x = f2bf(f.x); u.y = f2bf(f.y); u.z = f2bf(f.z); u.w = f2bf(f.w);
    d[i] = u;
  }
}

// ---------------- GEMM: C[M,N] = A[M,K] * Bt[N,K]^T + bias ----------------
struct GemmArgs {
  const unsigned short* A[3];
  const unsigned short* Bt[3];
  const float* bias[3];
  unsigned short* Cb[3];
  float* Cf[3];
  float scale[3];
  int vt[3];  // 1 => write bf16 output transposed per-head: vt[bh][d][kv]
};

template <bool BF16OUT>
__global__ __launch_bounds__(256) void gemm_bt_k(GemmArgs g) {
  const int z = blockIdx.z;
  const unsigned short* __restrict__ A = g.A[z];
  const unsigned short* __restrict__ Bt = g.Bt[z];
  const float* __restrict__ bias = g.bias[z];

  __shared__ unsigned short As[128 * 32];
  __shared__ unsigned short Bs[128 * 32];

  const int tid = threadIdx.x;
  const int lane = tid & 63;
  const int wave = tid >> 6;
  const int bm = blockIdx.x * 128;
  const int bn = blockIdx.y * 128;
  const int wm = (wave >> 1) * 64;
  const int wn = (wave & 1) * 64;

  const int srow = wave * 16 + (lane >> 2);
  const int scol = (lane & 3) * 8;
  const unsigned short* a_src = A + (size_t)(bm + srow) * DIMSZ + scol;
  const unsigned short* b_src = Bt + (size_t)(bn + srow) * DIMSZ + scol;
  char* a_dst = (char*)As + (size_t)(wave * 16) * 64;
  char* b_dst = (char*)Bs + (size_t)(wave * 16) * 64;

  const int fr = lane & 15;
  const int fk = (lane >> 4) * 8;

  f32x4 acc[4][4];
#pragma unroll
  for (int m = 0; m < 4; m++)
#pragma unroll
    for (int n = 0; n < 4; n++) acc[m][n] = (f32x4){0.f, 0.f, 0.f, 0.f};

  for (int k0 = 0; k0 < DIMSZ; k0 += 32) {
    __syncthreads();
    gload_lds16(a_src + k0, a_dst);
    gload_lds16(a_src + (size_t)64 * DIMSZ + k0, a_dst + 64 * 64);
    gload_lds16(b_src + k0, b_dst);
    gload_lds16(b_src + (size_t)64 * DIMSZ + k0, b_dst + 64 * 64);
    __syncthreads();

    short8 af[4], bfr[4];
#pragma unroll
    for (int m = 0; m < 4; m++) af[m] = *(const short8*)&As[(wm + m * 16 + fr) * 32 + fk];
#pragma unroll
    for (int n = 0; n < 4; n++) bfr[n] = *(const short8*)&Bs[(wn + n * 16 + fr) * 32 + fk];
#pragma unroll
    for (int m = 0; m < 4; m++)
#pragma unroll
      for (int n = 0; n < 4; n++) acc[m][n] = mfma16(af[m], bfr[n], acc[m][n]);
  }

  // epilogue: C/D layout col=lane&15, row=(lane>>4)*4+j (m89/m91-verified)
  const int r4 = (lane >> 4) * 4;
  const float sc = g.scale[z];
  if (g.vt[z]) {
    // write V^T per-head: vt[(b*16+h)*64 + d][kv], 4 consecutive rows packed
    unsigned short* vtp = g.Cb[z];
#pragma unroll
    for (int n = 0; n < 4; n++) {
      const int c = bn + wn + n * 16 + fr;
      const float bv = bias[c];
#pragma unroll
      for (int m = 0; m < 4; m++) {
        const int rr = bm + wm + m * 16 + r4;
        ushort4 u;
        u.x = f2bf((acc[m][n][0] + bv) * sc);
        u.y = f2bf((acc[m][n][1] + bv) * sc);
        u.z = f2bf((acc[m][n][2] + bv) * sc);
        u.w = f2bf((acc[m][n][3] + bv) * sc);
        const size_t idx =
            ((size_t)((rr >> 11) * NHEADS + (c >> 6)) * HD + (c & 63)) * SEQ + (rr & (SEQ - 1));
        *(ushort4*)&vtp[idx] = u;
      }
    }
  } else {
#pragma unroll
    for (int n = 0; n < 4; n++) {
      const int c = bn + wn + n * 16 + fr;
      const float bv = bias[c];
#pragma unroll
      for (int m = 0; m < 4; m++) {
#pragma unroll
        for (int j = 0; j < 4; j++) {
          const int r = bm + wm + m * 16 + r4 + j;
          const float val = (acc[m][n][j] + bv) * sc;
          if (BF16OUT)
            g.Cb[z][(size_t)r * DIMSZ + c] = f2bf(val);
          else
            g.Cf[z][(size_t)r * DIMSZ + c] = val;
        }
      }
    }
  }
}

// ---------------- fused attention ----------------
// grid (SEQ/128, 64 bh), 8 waves x 16 q-rows. Swapped QK^T; ONLINE-max softmax
// (round-2-verified numerics: per-tile max + sf rescale, dominant weight = 1.0
// exact); pi-permuted PV (A-frag = lane-local S values, no shuffles); manual
// f2bf packing; K/V^T via global_load_lds (pre-swizzled source), dbuf.
__global__ __launch_bounds__(512) void attn_k(const unsigned short* __restrict__ q,
                                              const unsigned short* __restrict__ k,
                                              const unsigned short* __restrict__ vt,
                                              unsigned short* __restrict__ o) {
  const int tid = threadIdx.x;
  const int lane = tid & 63;
  const int wave = tid >> 6;  // 0..7
  const int bh = blockIdx.y;
  const int b = bh >> 4;
  const int h = bh & 15;
  const int q0 = blockIdx.x * 128;

  __shared__ unsigned short Ks[2][64 * 64];
  __shared__ unsigned short Vs[2][64 * 64];

  const int fr = lane & 15;
  const int g4 = lane >> 4;
  const int fkb = g4 * 16;

  // Q fragments (Q pre-scaled by 0.125 in the projection GEMM)
  const size_t qrow = (size_t)b * SEQ + q0 + wave * 16 + fr;
  const unsigned short* qp = q + qrow * DIMSZ + h * HD + g4 * 8;
  const short8 qa0 = *(const short8*)(qp);
  const short8 qa1 = *(const short8*)(qp + 32);

  float m_run = -1e30f, l_run = 0.f;
  f32x4 oacc[4];
#pragma unroll
  for (int n = 0; n < 4; n++) oacc[n] = (f32x4){0.f, 0.f, 0.f, 0.f};

  // loop-invariant LDS read offsets
  int koff[4][2];   // QK^T: b128 reads of K rows
  int voff[4][4];   // PV: b64 reads of V^T rows at pi-slot offsets
#pragma unroll
  for (int n = 0; n < 4; n++) {
    const int row = fr + 16 * n;
    const int swz = swzfn(row);
    koff[n][0] = (row * 128 + fkb) ^ swz;
    koff[n][1] = (row * 128 + 64 + fkb) ^ swz;
#pragma unroll
    for (int c = 0; c < 4; c++) voff[n][c] = (row * 128 + (c * 32 + 8 * g4)) ^ swz;
  }

  // staging: 8 waves x 8 rows; linear LDS dest, pre-swizzled global source
  const int klrow = lane >> 3;
  const int kcb = (lane & 7) * 16;
  const int srow = wave * 8 + klrow;  // 0..63
  const int scol = (kcb ^ swzfn(srow)) >> 1;
  const unsigned short* ksrc =
      k + (size_t)b * SEQ * DIMSZ + h * HD + (size_t)srow * DIMSZ + scol;
  const unsigned short* vsrc =
      vt + (size_t)bh * HD * SEQ + (size_t)srow * SEQ + scol;

  auto stage = [&](int t, int buf) {
    const size_t kv0 = (size_t)t * 64;
    gload_lds16(ksrc + kv0 * DIMSZ, (char*)Ks[buf] + wave * 1024);
    gload_lds16(vsrc + kv0, (char*)Vs[buf] + wave * 1024);
  };

  stage(0, 0);
  __syncthreads();
  int cur = 0;

  for (int t = 0; t < SEQ / 64; ++t) {
    if (t + 1 < SEQ / 64) stage(t + 1, cur ^ 1);

    const char* Kc = (const char*)Ks[cur];
    const char* Vc = (const char*)Vs[cur];

    // S^T = K.Q^T : lane (fr,g4) holds S[kv = 16n + 4g4 + jj][q = fr]
    f32x4 s[4];
#pragma unroll
    for (int n = 0; n < 4; n++) {
      const short8 kb0 = *(const short8*)(Kc + koff[n][0]);
      const short8 kb1 = *(const short8*)(Kc + koff[n][1]);
      f32x4 tacc = (f32x4){0.f, 0.f, 0.f, 0.f};
      tacc = mfma16(kb0, qa0, tacc);
      tacc = mfma16(kb1, qa1, tacc);
      s[n] = tacc;
    }

    // online softmax for q-row fr: lane-local 16 values + 2 shfl for row max
    float pm = -1e30f;
#pragma unroll
    for (int n = 0; n < 4; n++)
#pragma unroll
      for (int jj = 0; jj < 4; jj++) pm = fmaxf(pm, s[n][jj]);
    pm = fmaxf(pm, __shfl_xor(pm, 16));
    pm = fmaxf(pm, __shfl_xor(pm, 32));
    const float mn = fmaxf(m_run, pm);
    const float sf = __expf(m_run - mn);
    m_run = mn;

    unsigned pu[4][2];
    float rs = 0.f;
#pragma unroll
    for (int n = 0; n < 4; n++) {
      const float p0 = __expf(s[n][0] - mn);
      const float p1 = __expf(s[n][1] - mn);
      const float p2 = __expf(s[n][2] - mn);
      const float p3 = __expf(s[n][3] - mn);
      rs += (p0 + p1) + (p2 + p3);
      pu[n][0] = (unsigned)f2bf(p0) | ((unsigned)f2bf(p1) << 16);
      pu[n][1] = (unsigned)f2bf(p2) | ((unsigned)f2bf(p3) << 16);
    }
    l_run = l_run * sf + rs;  // per-lane partial (row-sum deferred to epilogue)

    // rescale O (rows 4*g4+jj): gather sf of those rows (sf row-uniform)
    float sfr[4];
#pragma unroll
    for (int jj = 0; jj < 4; jj++) sfr[jj] = __shfl(sf, 20 * g4 + jj);
#pragma unroll
    for (int n = 0; n < 4; n++)
#pragma unroll
      for (int jj = 0; jj < 4; jj++) oacc[n][jj] *= sfr[jj];

    // pi-permuted A-fragments: slot k=8*g4+e  <->  kv = (e<4 ? 4g4+e : 16+4g4+e-4)
    // (+32 for pa1) — exactly the kv values this lane already holds. No shuffles.
    union { unsigned u[4]; short8 v; } pa0, pa1;
    pa0.u[0] = pu[0][0]; pa0.u[1] = pu[0][1]; pa0.u[2] = pu[1][0]; pa0.u[3] = pu[1][1];
    pa1.u[0] = pu[2][0]; pa1.u[1] = pu[2][1]; pa1.u[2] = pu[3][0]; pa1.u[3] = pu[3][1];

    // O += P V, B-frag read at matching pi-slot offsets (two b64 per frag)
#pragma unroll
    for (int n = 0; n < 4; n++) {
      union { short4v h[2]; short8 v; } vb0, vb1;
      vb0.h[0] = *(const short4v*)(Vc + voff[n][0]);
      vb0.h[1] = *(const short4v*)(Vc + voff[n][1]);
      vb1.h[0] = *(const short4v*)(Vc + voff[n][2]);
      vb1.h[1] = *(const short4v*)(Vc + voff[n][3]);
      oacc[n] = mfma16(pa0.v, vb0.v, oacc[n]);
      oacc[n] = mfma16(pa1.v, vb1.v, oacc[n]);
    }

    __syncthreads();  // next-tile staging complete; cur buffer free
    cur ^= 1;
  }

  // epilogue: reduce l across the 4 g4 copies, then O /= l
  l_run += __shfl_xor(l_run, 16);
  l_run += __shfl_xor(l_run, 32);
  float inv[4];
#pragma unroll
  for (int jj = 0; jj < 4; jj++) inv[jj] = 1.f / __shfl(l_run, 20 * g4 + jj);
#pragma unroll
  for (int n = 0; n < 4; n++)
#pragma unroll
    for (int jj = 0; jj < 4; jj++) {
      const int row = q0 + wave * 16 + 4 * g4 + jj;
      o[((size_t)bh * SEQ + row) * HD + fr + 16 * n] = f2bf(oacc[n][jj] * inv[jj]);
    }
}

// ---------------- launcher ----------------
extern "C" void kernel_launch(void* const* d_in, const int* in_sizes, int n_in,
                              void* d_out, int out_size, void* d_ws, size_t ws_size,
                              hipStream_t stream) {
  (void)in_sizes; (void)n_in; (void)out_size; (void)ws_size;
  const float* query = (const float*)d_in[0];
  const float* key_i = (const float*)d_in[1];
  const float* value = (const float*)d_in[2];
  const float* Wq = (const float*)d_in[3];
  const float* bq = (const float*)d_in[4];
  const float* Wk = (const float*)d_in[5];
  const float* bk = (const float*)d_in[6];
  const float* Wv = (const float*)d_in[7];
  const float* bv = (const float*)d_in[8];
  const float* Wo = (const float*)d_in[9];
  const float* bo = (const float*)d_in[10];
  float* out = (float*)d_out;

  char* ws = (char*)d_ws;
  size_t off = 0;
  auto alloc = [&](size_t bytes) -> char* {
    char* p = ws + off;
    off += (bytes + 255) & ~(size_t)255;
    return p;
  };
  const size_t big = (size_t)MR * DIMSZ * 2;      // 16.78 MB
  const size_t wsz = (size_t)DIMSZ * DIMSZ * 2;   // 2.1 MB
  unsigned short* xq = (unsigned short*)alloc(big);
  unsigned short* xk = (unsigned short*)alloc(big);
  unsigned short* xv = (unsigned short*)alloc(big);
  unsigned short* wqb = (unsigned short*)alloc(wsz);
  unsigned short* wkb = (unsigned short*)alloc(wsz);
  unsigned short* wvb = (unsigned short*)alloc(wsz);
  unsigned short* wob = (unsigned short*)alloc(wsz);
  unsigned short* qb = (unsigned short*)alloc(big);
  unsigned short* kb = (unsigned short*)alloc(big);
  unsigned short* vtb = (unsigned short*)alloc(big);  // V^T per-head [bh][d][kv]
  unsigned short* ob = xq;  // xq dead after QKV GEMM

  // 1) convert inputs + weights to bf16
  Cvt7 ca;
  ca.s[0] = query; ca.d[0] = xq; ca.n4[0] = MR * DIMSZ / 4;
  ca.s[1] = key_i; ca.d[1] = xk; ca.n4[1] = MR * DIMSZ / 4;
  ca.s[2] = value; ca.d[2] = xv; ca.n4[2] = MR * DIMSZ / 4;
  ca.s[3] = Wq;    ca.d[3] = wqb; ca.n4[3] = DIMSZ * DIMSZ / 4;
  ca.s[4] = Wk;    ca.d[4] = wkb; ca.n4[4] = DIMSZ * DIMSZ / 4;
  ca.s[5] = Wv;    ca.d[5] = wvb; ca.n4[5] = DIMSZ * DIMSZ / 4;
  ca.s[6] = Wo;    ca.d[6] = wob; ca.n4[6] = DIMSZ * DIMSZ / 4;
  cvt7_k<<<dim3(1024, 7), 256, 0, stream>>>(ca);

  // 2) QKV projections (z-fused); Q pre-scaled by 0.125; V written transposed
  GemmArgs gp;
  gp.A[0] = xq; gp.A[1] = xk; gp.A[2] = xv;
  gp.Bt[0] = wqb; gp.Bt[1] = wkb; gp.Bt[2] = wvb;
  gp.bias[0] = bq; gp.bias[1] = bk; gp.bias[2] = bv;
  gp.Cb[0] = qb; gp.Cb[1] = kb; gp.Cb[2] = vtb;
  gp.Cf[0] = nullptr; gp.Cf[1] = nullptr; gp.Cf[2] = nullptr;
  gp.scale[0] = 0.125f; gp.scale[1] = 1.f; gp.scale[2] = 1.f;
  gp.vt[0] = 0; gp.vt[1] = 0; gp.vt[2] = 1;
  gemm_bt_k<true><<<dim3(MR / 128, DIMSZ / 128, 3), 256, 0, stream>>>(gp);

  // 3) fused attention
  attn_k<<<dim3(SEQ / 128, BATCH * NHEADS), 512, 0, stream>>>(qb, kb, vtb, ob);

  // 4) output projection (fp32 out + bias)
  GemmArgs go;
  go.A[0] = ob; go.A[1] = ob; go.A[2] = ob;
  go.Bt[0] = wob; go.Bt[1] = wob; go.Bt[2] = wob;
  go.bias[0] = bo; go.bias[1] = bo; go.bias[2] = bo;
  go.Cb[0] = nullptr; go.Cb[1] = nullptr; go.Cb[2] = nullptr;
  go.Cf[0] = out; go.Cf[1] = out; go.Cf[2] = out;
  go.scale[0] = 1.f; go.scale[1] = 1.f; go.scale[2] = 1.f;
  go.vt[0] = 0; go.vt[1] = 0; go.vt[2] = 0;
  gemm_bt_k<false><<<dim3(MR / 128, DIMSZ / 128, 1), 256, 0, stream>>>(go);
}